// Round 4
// baseline (462.207 us; speedup 1.0000x reference)
//
#include <hip/hip_runtime.h>
#include <hip/hip_fp16.h>

// ConformalGCN: 2-layer GCN, N=100000, E=1600000 (+self loops).
// R3: (1) CSR record 8B->4B (weights folded into dinv-prescaled rows),
//     (2) fp16-packed feature rows for the gather (halves agg fetch),
//     (3) gemm2 fused into layer-2 agg via LDS, calc_dinv folded into
//         add_offsets. fp32 accumulation everywhere.
//
// Feature/lane layout for packed rows (32 u32 words per node):
//   word w holds features (2w lo, 2w+1 hi); lane l owns f = 2*(l&31)+(l>>5).

#define IN_F  128
#define HID_F 64
#define OUT_F 96

__device__ __forceinline__ float h2f_sel(unsigned u, unsigned sh) {
    unsigned short us = (unsigned short)(u >> sh);
    __half h = *reinterpret_cast<__half*>(&us);
    return __half2float(h);
}
__device__ __forceinline__ unsigned f2h2(float lo, float hi) {
    __half2 h = __floats2half2_rn(lo, hi);
    return *reinterpret_cast<unsigned*>(&h);
}

__global__ __launch_bounds__(256) void zero_deg(int* __restrict__ deg, int n) {
    for (int i = blockIdx.x * 256 + threadIdx.x; i < n; i += gridDim.x * 256)
        deg[i] = 0;
}

__global__ __launch_bounds__(256) void count_deg(const int* __restrict__ dst,
                                                 int* __restrict__ deg, int E) {
    for (int e = blockIdx.x * 256 + threadIdx.x; e < E; e += gridDim.x * 256)
        atomicAdd(&deg[dst[e]], 1);
}

// ---- hierarchical exclusive prefix sum over deg[n] (1024 elems/block) ----
__global__ __launch_bounds__(256) void scan_blocks(const int* __restrict__ deg,
                                                   int* __restrict__ pre,
                                                   int* __restrict__ bsum, int n) {
    __shared__ int lds[256];
    const int t = threadIdx.x;
    const int base = blockIdx.x * 1024 + t * 4;
    int v0 = (base + 0 < n) ? deg[base + 0] : 0;
    int v1 = (base + 1 < n) ? deg[base + 1] : 0;
    int v2 = (base + 2 < n) ? deg[base + 2] : 0;
    int v3 = (base + 3 < n) ? deg[base + 3] : 0;
    int s = v0 + v1 + v2 + v3;
    lds[t] = s;
    __syncthreads();
    for (int off = 1; off < 256; off <<= 1) {
        int add = (t >= off) ? lds[t - off] : 0;
        __syncthreads();
        lds[t] += add;
        __syncthreads();
    }
    int e = lds[t] - s;
    if (base + 0 < n) pre[base + 0] = e;
    e += v0;
    if (base + 1 < n) pre[base + 1] = e;
    e += v1;
    if (base + 2 < n) pre[base + 2] = e;
    e += v2;
    if (base + 3 < n) pre[base + 3] = e;
    if (t == 255) bsum[blockIdx.x] = lds[255];
}

__global__ __launch_bounds__(256) void scan_bsums(const int* __restrict__ bsum,
                                                  int* __restrict__ boffs, int nb) {
    __shared__ int lds[256];
    const int t = threadIdx.x;
    int v = (t < nb) ? bsum[t] : 0;
    lds[t] = v;
    __syncthreads();
    for (int off = 1; off < 256; off <<= 1) {
        int add = (t >= off) ? lds[t - off] : 0;
        __syncthreads();
        lds[t] += add;
        __syncthreads();
    }
    boffs[t] = lds[t] - v;
}

__global__ __launch_bounds__(256) void add_offsets(const int* __restrict__ pre,
                                                   const int* __restrict__ boffs,
                                                   const int* __restrict__ deg,
                                                   int* __restrict__ rowptr,
                                                   int* __restrict__ writepos,
                                                   float* __restrict__ dinv,
                                                   int n, int E) {
    for (int i = blockIdx.x * 256 + threadIdx.x; i < n; i += gridDim.x * 256) {
        int r = pre[i] + boffs[i >> 10];
        rowptr[i] = r;
        writepos[i] = r;
        dinv[i] = rsqrtf((float)(deg[i] + 1));   // +1 self loop
        if (i == 0) rowptr[n] = E;
    }
}

// csr_src[pos] = src   (4B record; weight folded into prescaled rows)
__global__ __launch_bounds__(256) void fill_csr(const int* __restrict__ src,
                                                const int* __restrict__ dst,
                                                int* __restrict__ writepos,
                                                int* __restrict__ csr_src, int E) {
    for (int e = blockIdx.x * 256 + threadIdx.x; e < E; e += gridDim.x * 256) {
        int pos = atomicAdd(&writepos[dst[e]], 1);
        csr_src[pos] = src[e];
    }
}

// hs[row] = fp16x2-packed( dinv[row] * (x[row] @ W1) ).  Wave per row, lane=col.
__global__ __launch_bounds__(256) void gemm1(const float* __restrict__ x,
                                             const float* __restrict__ W1,
                                             const float* __restrict__ dinv,
                                             unsigned* __restrict__ hs, int n) {
    __shared__ float w[IN_F * HID_F];   // 32 KiB
    __shared__ float xs[4][IN_F];
    for (int i = threadIdx.x; i < IN_F * HID_F; i += 256) w[i] = W1[i];
    __syncthreads();
    const int wave = threadIdx.x >> 6, lane = threadIdx.x & 63;
    for (int row = blockIdx.x * 4 + wave; row < n; row += gridDim.x * 4) {
        float2 v = *(const float2*)(x + (size_t)row * IN_F + lane * 2);
        xs[wave][lane * 2]     = v.x;
        xs[wave][lane * 2 + 1] = v.y;
        float acc = 0.f;
#pragma unroll 8
        for (int k = 0; k < IN_F; ++k)
            acc = fmaf(xs[wave][k], w[k * HID_F + lane], acc);
        acc *= dinv[row];
        float other = __shfl_xor(acc, 1);      // partner feature
        if (!(lane & 1))                       // even lane: features (l, l+1) -> word l/2
            hs[(size_t)row * 32 + (lane >> 1)] = f2h2(acc, other);
    }
}

// One wave per node, 4 nodes/block. acc = sum of prescaled fp16 rows (+self),
// result * dinv[node].  LAYER 1: +bias, relu, re-scale, pack fp16 out.
// LAYER 2: fused gemm2 (a2 @ W2 + b2) through LDS -> d_out.
template <int LAYER>
__global__ __launch_bounds__(256) void csr_agg(const int* __restrict__ rowptr,
                                               const int* __restrict__ csr_src,
                                               const float* __restrict__ dinv,
                                               const unsigned* __restrict__ hs,
                                               const float* __restrict__ b1,
                                               unsigned* __restrict__ hs2,
                                               const float* __restrict__ W2,
                                               const float* __restrict__ b2,
                                               float* __restrict__ out,
                                               int n, int nquad) {
    __shared__ float w2s[LAYER == 2 ? HID_F * OUT_F : 1];   // 24 KiB (layer 2)
    __shared__ float b2s[LAYER == 2 ? OUT_F : 1];
    __shared__ float arow[LAYER == 2 ? 4 : 1][LAYER == 2 ? HID_F : 1];

    const int wave = threadIdx.x >> 6, lane = threadIdx.x & 63;
    const int wrd = lane & 31;
    const unsigned hshift = (lane & 32) ? 16u : 0u;   // hi/lo half select
    const int feat = 2 * wrd + (lane >> 5);

    if (LAYER == 2) {
        for (int i = threadIdx.x; i < HID_F * OUT_F; i += 256) w2s[i] = W2[i];
        for (int i = threadIdx.x; i < OUT_F; i += 256) b2s[i] = b2[i];
        __syncthreads();
    }
    const float b1f = (LAYER == 1) ? b1[feat] : 0.f;

    for (int q = blockIdx.x; q < nquad; q += gridDim.x) {
        const int node = q * 4 + wave;
        const bool valid = node < n;
        float acc0 = 0.f, acc1 = 0.f, dn = 0.f;
        if (valid) {
            const int beg = rowptr[node], end = rowptr[node + 1];
            dn = dinv[node];
            acc0 = h2f_sel(hs[(size_t)node * 32 + wrd], hshift);   // self loop
            int p = beg;
#define GATHER(i) int s##i = csr_src[p + i]; unsigned u##i = hs[(size_t)s##i * 32 + wrd];
            for (; p + 8 <= end; p += 8) {
                GATHER(0) GATHER(1) GATHER(2) GATHER(3)
                GATHER(4) GATHER(5) GATHER(6) GATHER(7)
                acc0 += h2f_sel(u0, hshift);
                acc1 += h2f_sel(u1, hshift);
                acc0 += h2f_sel(u2, hshift);
                acc1 += h2f_sel(u3, hshift);
                acc0 += h2f_sel(u4, hshift);
                acc1 += h2f_sel(u5, hshift);
                acc0 += h2f_sel(u6, hshift);
                acc1 += h2f_sel(u7, hshift);
            }
            if (p + 4 <= end) {
                GATHER(0) GATHER(1) GATHER(2) GATHER(3)
                acc0 += h2f_sel(u0, hshift);
                acc1 += h2f_sel(u1, hshift);
                acc0 += h2f_sel(u2, hshift);
                acc1 += h2f_sel(u3, hshift);
                p += 4;
            }
            for (; p < end; ++p) {
                GATHER(0)
                acc0 += h2f_sel(u0, hshift);
            }
#undef GATHER
        }
        const float acc = acc0 + acc1;

        if (LAYER == 1) {
            float v = fmaxf(dn * acc + b1f, 0.f) * dn;   // relu(a1+b1), prescale for L2
            float vhi = __shfl_xor(v, 32);               // feature 2*wrd+1 partner
            if (valid && (lane & 32) == 0)
                hs2[(size_t)node * 32 + wrd] = f2h2(v, vhi);
        } else {
            arow[wave][feat] = dn * acc;                 // a2 row (garbage ok if !valid)
            __syncthreads();
            const int qbase = q * 4;
            for (int idx = threadIdx.x; idx < 4 * OUT_F; idx += 256) {
                int qq = idx / OUT_F, j = idx - qq * OUT_F;
                int nd = qbase + qq;
                if (nd < n) {
                    float s = b2s[j];
#pragma unroll
                    for (int k = 0; k < HID_F; ++k)
                        s = fmaf(arow[qq][k], w2s[k * OUT_F + j], s);
                    out[(size_t)nd * OUT_F + j] = s;
                }
            }
            __syncthreads();
        }
    }
}

extern "C" void kernel_launch(void* const* d_in, const int* in_sizes, int n_in,
                              void* d_out, int out_size, void* d_ws, size_t ws_size,
                              hipStream_t stream) {
    const float* x  = (const float*)d_in[0];
    const int*   ei = (const int*)d_in[1];
    const float* W1 = (const float*)d_in[2];
    const float* b1 = (const float*)d_in[3];
    const float* W2 = (const float*)d_in[4];
    const float* b2 = (const float*)d_in[5];
    float* out = (float*)d_out;

    const int n = in_sizes[0] / IN_F;     // 100000
    const int E = in_sizes[1] / 2;        // 1600000
    const int* src = ei;
    const int* dst = ei + E;
    const int NB = (n + 1023) / 1024;     // scan blocks (98)
    const int nquad = (n + 3) / 4;        // 25000

    char* ws = (char*)d_ws;
    size_t off = 0;
    auto alloc = [&](size_t bytes) { void* p = ws + off; off = (off + bytes + 255) & ~(size_t)255; return p; };
    int*      deg      = (int*)alloc((size_t)n * 4);
    float*    dinv     = (float*)alloc((size_t)n * 4);
    int*      pre      = (int*)alloc((size_t)n * 4);
    int*      rowptr   = (int*)alloc((size_t)(n + 1) * 4);
    int*      writepos = (int*)alloc((size_t)n * 4);
    int*      bsum     = (int*)alloc(256 * 4);
    int*      boffs    = (int*)alloc(256 * 4);
    int*      csr_src  = (int*)alloc((size_t)E * 4);
    unsigned* hs       = (unsigned*)alloc((size_t)n * 32 * 4);
    unsigned* hs2      = (unsigned*)alloc((size_t)n * 32 * 4);

    zero_deg   <<<512, 256, 0, stream>>>(deg, n);
    count_deg  <<<2048, 256, 0, stream>>>(dst, deg, E);
    scan_blocks<<<NB, 256, 0, stream>>>(deg, pre, bsum, n);
    scan_bsums <<<1, 256, 0, stream>>>(bsum, boffs, NB);
    add_offsets<<<512, 256, 0, stream>>>(pre, boffs, deg, rowptr, writepos, dinv, n, E);
    fill_csr   <<<2048, 256, 0, stream>>>(src, dst, writepos, csr_src, E);

    gemm1      <<<2048, 256, 0, stream>>>(x, W1, dinv, hs, n);
    csr_agg<1> <<<nquad, 256, 0, stream>>>(rowptr, csr_src, dinv, hs, b1, hs2,
                                           NULL, NULL, NULL, n, nquad);
    csr_agg<2> <<<2048, 256, 0, stream>>>(rowptr, csr_src, dinv, hs2, NULL, NULL,
                                          W2, b2, out, n, nquad);
}